// Round 15
// baseline (140.887 us; speedup 1.0000x reference)
//
#include <hip/hip_runtime.h>

// hybridloss: arcface CE (512x100000x128 fp8-MFMA GEMM + exp-sum softmax)
//           + TV loss + bin loss + sum|FFT2(k)| (1024x1024, REAL input).
// R15 = R14 (139.6us best) + one more notch on the two validated dials:
//   (1) normW: 64 rows/block, 4 rows per 16-lane group (stage1 3768 -> 2204 blocks);
//   (2) gemmred: 128 reduce blocks, 25-deep chains, g2[64][512] (was 64 / 49-deep).
//   Frozen: fp8 1-barrier gemm + XCD mod-8 grouping, row-pair real FFT + Hermitian
//   column halving, tvbin as stage2 role, last-block-done final.
// Workspace layout (bytes), total ~20.46 MB (ws is 256 MiB):
//   [0,2048)              coslab[512]
//   [2048,67584)          xh8: 512x128 fp8
//   [67584,12879872)      Wh8: 100096x128 fp8 (pad rows zeroed)
//   [12879872,17106944)   fbuf: 1024 rows x 516 cols float2
//   [17106944,20310016)   gpart[1564][512]
//   [20310016,20441088)   g2[64][512]
//   [20441088,20457472)   tvpart[1024] float4
//   [20457472,20459520)   fftpart[129] (padded)
//   [20459520,20461568)   labexp[512]
//   [20461568,20461572)   cnt (last-block counter, zeroed by stage1)

typedef float f32x4 __attribute__((ext_vector_type(4)));
typedef unsigned short u16;
typedef unsigned int u32;
typedef unsigned long long u64;

#define BATCH 512
#define DIM 128
#define OUTN 100000
#define NOBLK 782
#define NROW2 1564      // gpart rows
#define CHUNKS 64
#define CHSZ2 25        // 64*25 = 1600 >= 1564
#define NCOL 516
#define SSCALE 32.0f
#define K2C 46.166241308446828f   // 32 * log2(e)
#define COSM 0.8775825618903728f
#define SINM 0.479425538604203f
#define THC (-0.8775825618903728f)
#define MMC 0.2397127693021015f

// stage1 roles (blockIdx.x): fftrow(pairs) | xprep | normW (64 rows/block)
#define S1_FFT 512
#define S1_XP  640
#define S1_NW  2204    // 640 + 1564 (64 W-rows per block; 1564*64 = 100096)

// stage2 roles: [0,129) fftcol; [129,129+3136) gemm (98 groups of 32); then tvbin
#define S2_GEMM0 129
#define S2_TV0   3265
#define S2_NBLK  4289

// gemmred: blocks 0..127 reduce, 128..129 labexp; last of 130 finalizes
#define GR_NBLK 130

#define DEC8(v, j) __builtin_amdgcn_cvt_f32_fp8((int)(v), (j))

__device__ inline float waveRedSum(float v) {
#pragma unroll
  for (int off = 1; off < 64; off <<= 1) v += __shfl_xor(v, off, 64);
  return v;
}

__device__ inline float quadRedSum(float v) {   // reduce within each 16-lane group
#pragma unroll
  for (int off = 1; off < 16; off <<= 1) v += __shfl_xor(v, off, 64);
  return v;
}

// ---------------- stage 1: fftrow-pairs | xprep | normW ----------------
__global__ __launch_bounds__(256) void stage1_k(const float* __restrict__ x,
                                                const float* __restrict__ W,
                                                const int* __restrict__ label,
                                                const float* __restrict__ kimg,
                                                char* __restrict__ xh8,
                                                float* __restrict__ coslab,
                                                char* __restrict__ Wh8,
                                                float2* __restrict__ fbuf,
                                                int* __restrict__ cnt) {
  __shared__ __align__(16) char smem[12288];   // tw[512]f2 + arr[1024]f2
  int t = threadIdx.x;
  int bid = blockIdx.x;

  if (bid < S1_FFT) {
    // ---- row-pair FFT: z = row(2r) + i*row(2r+1), 1024-pt DIF, Hermitian unpack ----
    float2* tw = (float2*)smem;          // tw[j] = (cos,sin)(-2*pi*j/1024)
    float2* arr = (float2*)(smem + 4096);
    int r = bid;
#pragma unroll
    for (int i = 0; i < 2; i++) {
      int j = i * 256 + t;
      float s, c;
      __sincosf(-0.006135923151542565f * (float)j, &s, &c);  // -2pi/1024 * j
      tw[j] = make_float2(c, s);
    }
#pragma unroll
    for (int i = 0; i < 4; i++) {
      int idx = i * 256 + t;
      arr[idx] = make_float2(kimg[(2 * r) * 1024 + idx], kimg[(2 * r + 1) * 1024 + idx]);
    }
    __syncthreads();
    for (int lh = 9; lh >= 0; lh--) {
      int hlf = 1 << lh;
#pragma unroll
      for (int i = 0; i < 2; i++) {
        int bf = i * 256 + t;
        int pos = bf & (hlf - 1);
        int g = bf >> lh;
        int i0 = (g << (lh + 1)) + pos;
        int i1 = i0 + hlf;
        float2 u = arr[i0], v = arr[i1];
        float2 w = tw[pos << (9 - lh)];
        arr[i0] = make_float2(u.x + v.x, u.y + v.y);
        float dr = u.x - v.x, di = u.y - v.y;
        arr[i1] = make_float2(dr * w.x - di * w.y, dr * w.y + di * w.x);
      }
      __syncthreads();
    }
    // arr[br10(k)] = Z(k). Unpack k=0..512 (cols 513..515 zeroed).
#pragma unroll
    for (int it = 0; it < 3; it++) {
      int k = it * 256 + t;
      if (k < NCOL) {
        float2 fa = make_float2(0.f, 0.f), fb = make_float2(0.f, 0.f);
        if (k < 513) {
          int j1 = __brev((u32)k) >> 22;
          int j2 = __brev((u32)((1024 - k) & 1023)) >> 22;
          float2 z1 = arr[j1], z2 = arr[j2];
          fa = make_float2(0.5f * (z1.x + z2.x), 0.5f * (z1.y - z2.y));
          float uu = z1.x - z2.x, vv = z1.y + z2.y;
          fb = make_float2(0.5f * vv, -0.5f * uu);
        }
        fbuf[(size_t)(2 * r) * NCOL + k] = fa;
        fbuf[(size_t)(2 * r + 1) * NCOL + k] = fb;
      }
    }
  } else if (bid < S1_XP) {
    // ---- x normalize -> fp8 + fp32 cosine(x_b, W[label_b]) ----
    if (bid == S1_FFT && t == 0) *cnt = 0;   // zero the last-block counter
    int b = (bid - S1_FFT) * 4 + (t >> 6);
    int lane = t & 63;
    size_t xb = (size_t)b * DIM;
    float2 v = *(const float2*)&x[xb + lane * 2];
    int lab = label[b];
    size_t wb = (size_t)lab * DIM;
    float2 w = *(const float2*)&W[wb + lane * 2];
    float ss = waveRedSum(v.x * v.x + v.y * v.y);
    float d  = waveRedSum(v.x * w.x + v.y * w.y);
    float nw = waveRedSum(w.x * w.x + w.y * w.y);
    float inv = rsqrtf(ss);
    u32 pk = __builtin_amdgcn_cvt_pk_fp8_f32(v.x * inv, v.y * inv, 0, 0);
    *(u16*)&xh8[b * 128 + lane * 2] = (u16)pk;
    if (lane == 0) coslab[b] = d * rsqrtf(ss * nw);
  } else {
    // ---- W normalize -> fp8: 64 rows/block, 4 rows per 16-lane group ----
    int rA = (bid - S1_XP) * 64 + (t >> 4) * 4;   // rows rA..rA+3 (OUTN%4==0 -> uniform)
    int g16 = t & 15;
    if (rA >= OUTN) {
#pragma unroll
      for (int rr = 0; rr < 4; rr++)
        *(uint2*)&Wh8[(size_t)(rA + rr) * 128 + g16 * 8] = make_uint2(0u, 0u);
      return;
    }
#pragma unroll
    for (int rr = 0; rr < 4; rr++) {
      const float* wr = &W[(size_t)(rA + rr) * DIM + g16 * 8];
      float4 v0 = *(const float4*)wr;
      float4 v1 = *(const float4*)(wr + 4);
      float ss = quadRedSum(v0.x * v0.x + v0.y * v0.y + v0.z * v0.z + v0.w * v0.w
                          + v1.x * v1.x + v1.y * v1.y + v1.z * v1.z + v1.w * v1.w);
      float inv = rsqrtf(ss);
      u32 lo = __builtin_amdgcn_cvt_pk_fp8_f32(v0.x * inv, v0.y * inv, 0, 0);
      lo = __builtin_amdgcn_cvt_pk_fp8_f32(v0.z * inv, v0.w * inv, lo, 1);
      u32 hi = __builtin_amdgcn_cvt_pk_fp8_f32(v1.x * inv, v1.y * inv, 0, 0);
      hi = __builtin_amdgcn_cvt_pk_fp8_f32(v1.z * inv, v1.w * inv, hi, 1);
      *(uint2*)&Wh8[(size_t)(rA + rr) * 128 + g16 * 8] = make_uint2(lo, hi);
    }
  }
}

// ---------------- stage 2: fftcol(129) | fp8 gemm (1 barrier) | tvbin ----------------
__global__ __launch_bounds__(256, 4) void stage2_k(const char* __restrict__ Wh8,
                                                   const char* __restrict__ xh8,
                                                   float* __restrict__ gpart,
                                                   const float2* __restrict__ fbuf,
                                                   float* __restrict__ fftpart,
                                                   const float* __restrict__ kimg,
                                                   float4* __restrict__ tvpart) {
  __shared__ __align__(16) char smem[36880];
  int t = threadIdx.x;
  int bid = blockIdx.x;

  if (bid >= S2_TV0) {
    // ---- TV + bin loss, one image row per block ----
    int r = bid - S2_TV0;
    int idx = r * 1024 + t * 4;
    float4 v = *(const float4*)&kimg[idx];
    float bs = v.x * v.x + (v.x - 1.f) * (v.x - 1.f)
             + v.y * v.y + (v.y - 1.f) * (v.y - 1.f)
             + v.z * v.z + (v.z - 1.f) * (v.z - 1.f)
             + v.w * v.w + (v.w - 1.f) * (v.w - 1.f);
    float d0 = v.y - v.x, d1 = v.z - v.y, d2 = v.w - v.z;
    float wsm = d0 * d0 + d1 * d1 + d2 * d2;
    if (t < 255) { float e4 = kimg[idx + 4]; float d3 = e4 - v.w; wsm += d3 * d3; }
    float hs = 0.f;
    if (r < 1023) {
      float4 n = *(const float4*)&kimg[idx + 1024];
      float h0 = n.x - v.x, h1 = n.y - v.y, h2 = n.z - v.z, h3 = n.w - v.w;
      hs = h0 * h0 + h1 * h1 + h2 * h2 + h3 * h3;
    }
    hs = waveRedSum(hs); wsm = waveRedSum(wsm); bs = waveRedSum(bs);
    float (*red)[4] = (float(*)[4])smem;
    if ((t & 63) == 0) { int w = t >> 6; red[0][w] = hs; red[1][w] = wsm; red[2][w] = bs; }
    __syncthreads();
    if (t == 0)
      tvpart[r] = make_float4(red[0][0] + red[0][1] + red[0][2] + red[0][3],
                              red[1][0] + red[1][1] + red[1][2] + red[1][3],
                              red[2][0] + red[2][1] + red[2][2] + red[2][3], 0.f);
  } else if (bid >= S2_GEMM0) {
    // ---- GEMM role: 128(o) x 128(b), K=128 fp8, both tiles full-K in LDS ----
    int wgrp = (bid - S2_GEMM0) & 31, g = (bid - S2_GEMM0) >> 5;
    int o = g * 8 + (wgrp & 7), bt = wgrp >> 3;  // same-o blocks 8 apart -> same XCD
    if (o >= NOBLK) return;
    int o0 = o * 128, b0 = bt * 128;
    char* Ash = smem;                 // 128 rows x 16 chunks(8B), chunk' = c ^ (r&15)
    char* Bsh = smem + 16384;
    int wv = t >> 6, lane = t & 63;
    int wo = (wv & 1) << 6, wbs = (wv >> 1) << 6;
    int m16 = lane & 15, q = lane >> 4;

    // Stage both tiles (16 KB each), then ONE barrier.
    int r8 = t >> 3, cB = (t & 7) * 16, c0 = (t & 7) * 2;
#pragma unroll
    for (int it = 0; it < 4; it++) {
      int r = it * 32 + r8;
      int s = r & 15;
      uint4 va = *(const uint4*)&Wh8[(size_t)(o0 + r) * 128 + cB];
      *(u64*)&Ash[r * 128 + ((c0 ^ s) << 3)]       = ((u64)va.y << 32) | va.x;
      *(u64*)&Ash[r * 128 + (((c0 + 1) ^ s) << 3)] = ((u64)va.w << 32) | va.z;
      uint4 vb = *(const uint4*)&xh8[(size_t)(b0 + r) * 128 + cB];
      *(u64*)&Bsh[r * 128 + ((c0 ^ s) << 3)]       = ((u64)vb.y << 32) | vb.x;
      *(u64*)&Bsh[r * 128 + (((c0 + 1) ^ s) << 3)] = ((u64)vb.w << 32) | vb.z;
    }
    __syncthreads();

    f32x4 acc[4][4] = {};
#pragma unroll
    for (int kk = 0; kk < 4; kk++) {
      long af[4], bf[4];
#pragma unroll
      for (int i = 0; i < 4; i++) {
        int row = wo + i * 16 + m16;
        af[i] = *(const long*)&Ash[row * 128 + (((kk * 4 + q) ^ (row & 15)) << 3)];
      }
#pragma unroll
      for (int j = 0; j < 4; j++) {
        int row = wbs + j * 16 + m16;
        bf[j] = *(const long*)&Bsh[row * 128 + (((kk * 4 + q) ^ (row & 15)) << 3)];
      }
#pragma unroll
      for (int i = 0; i < 4; i++)
#pragma unroll
        for (int j = 0; j < 4; j++)
          acc[i][j] = __builtin_amdgcn_mfma_f32_16x16x32_fp8_fp8(af[i], bf[j], acc[i][j], 0, 0, 0);
    }
    // Epilogue: unmasked exp2 sums (pad rows -> exp2(0)=1, subtracted in final).
#pragma unroll
    for (int j = 0; j < 4; j++) {
      float s = 0.f;
#pragma unroll
      for (int i = 0; i < 4; i++)
#pragma unroll
        for (int r = 0; r < 4; r++)
          s += exp2f(K2C * acc[i][j][r]);
      s += __shfl_xor(s, 16, 64);   // fold q-quadrants (same b, different o)
      s += __shfl_xor(s, 32, 64);
      if (q == 0)
        gpart[(size_t)(o * 2 + (wv & 1)) * 512 + b0 + wbs + j * 16 + m16] = s;
    }
  } else {
    // ---- column FFT role (bids 0..128): 4 cols/block of fbuf[1024][516],
    //      weights: col0 & col512 x1, cols 1..511 x2, cols 513+ zero data ----
    float2* arr = (float2*)smem;          // 4096 float2 = 32 KB
    float2* tw = (float2*)(smem + 32768); // 512 float2 = 4 KB
    float* red = (float*)(smem + 36864);
    int c0 = bid * 4;
#pragma unroll
    for (int i = 0; i < 2; i++) {
      int j = i * 256 + t;
      float s, c;
      __sincosf(-0.006135923151542565f * (float)j, &s, &c);  // -2pi/1024 * j
      tw[j] = make_float2(c, s);
    }
#pragma unroll
    for (int i = 0; i < 16; i++) {
      int li = i * 256 + t;
      int rr = li >> 2, c = li & 3;
      arr[rr * 4 + c] = fbuf[(size_t)rr * NCOL + c0 + c];
    }
    __syncthreads();
    for (int lh = 9; lh >= 0; lh--) {
      int hlf = 1 << lh;
#pragma unroll
      for (int i = 0; i < 8; i++) {
        int w = i * 256 + t;
        int c = w & 3, bf = w >> 2;
        int pos = bf & (hlf - 1), g2i = bf >> lh;
        int i0 = ((g2i << (lh + 1)) + pos) * 4 + c;
        int i1 = i0 + hlf * 4;
        float2 u = arr[i0], v = arr[i1];
        float2 tww = tw[pos << (9 - lh)];
        arr[i0] = make_float2(u.x + v.x, u.y + v.y);
        float dr = u.x - v.x, di = u.y - v.y;
        arr[i1] = make_float2(dr * tww.x - di * tww.y, dr * tww.y + di * tww.x);
      }
      __syncthreads();
    }
    float s = 0.f;
#pragma unroll
    for (int i = 0; i < 16; i++) {
      int li = i * 256 + t;
      int col = c0 + (li & 3);
      float w = (col == 0 || col == 512) ? 1.f : (col < 512 ? 2.f : 0.f);
      float2 v = arr[li];
      s += w * sqrtf(v.x * v.x + v.y * v.y);
    }
    s = waveRedSum(s);
    if ((t & 63) == 0) red[t >> 6] = s;
    __syncthreads();
    if (t == 0) fftpart[bid] = red[0] + red[1] + red[2] + red[3];
  }
}

// blocks 0..127: reduce gpart -> g2[64][512]; blocks 128..129: labexp.
// LAST block to finish (device atomic) computes the final scalar loss.
__global__ __launch_bounds__(256) void gemmred_k(const float* __restrict__ gpart,
                                                 float* __restrict__ g2,
                                                 const char* __restrict__ xh8,
                                                 const char* __restrict__ Wh8,
                                                 const int* __restrict__ label,
                                                 float* __restrict__ labexp,
                                                 const float* __restrict__ coslab,
                                                 const float4* __restrict__ tvpart,
                                                 const float* __restrict__ fftpart,
                                                 int* __restrict__ cnt,
                                                 float* __restrict__ out) {
  int t = threadIdx.x;
  int blk = blockIdx.x;
  if (blk < 128) {
    int chunk = blk >> 1, half = blk & 1;
    int b = half * 256 + t;
    int rBeg = chunk * CHSZ2;
    int rEnd = rBeg + CHSZ2; if (rEnd > NROW2) rEnd = NROW2;
    float s = 0.f;
    for (int r = rBeg; r < rEnd; r++) s += gpart[(size_t)r * 512 + b];
    g2[chunk * 512 + b] = s;
  } else {
    int b = (blk - 128) * 256 + t;
    int lab = label[b];
    const u32* xr = (const u32*)(xh8 + (size_t)b * 128);
    const u32* wr = (const u32*)(Wh8 + (size_t)lab * 128);
    float d = 0.f;
#pragma unroll 4
    for (int i = 0; i < 32; i++) {
      u32 xa = xr[i], wa = wr[i];
      d += DEC8(xa, 0) * DEC8(wa, 0) + DEC8(xa, 1) * DEC8(wa, 1)
         + DEC8(xa, 2) * DEC8(wa, 2) + DEC8(xa, 3) * DEC8(wa, 3);
    }
    labexp[b] = exp2f(K2C * d);
  }

  // ---- last-block-done final reduction ----
  __shared__ int lastFlag;
  __threadfence();                       // release: g2/labexp visible device-wide
  __syncthreads();
  if (t == 0) lastFlag = (atomicAdd(cnt, 1) == GR_NBLK - 1);
  __syncthreads();
  if (!lastFlag) return;
  __threadfence();                       // acquire

  float arc = 0.f, hs = 0.f, wsm = 0.f, bs = 0.f, fs = 0.f;
#pragma unroll
  for (int i = 0; i < 2; i++) {
    int b = i * 256 + t;
    float se = 0.f;
#pragma unroll
    for (int c = 0; c < CHUNKS; c++) se += g2[c * 512 + b];
    se -= 96.0f;            // 100096-100000 zero rows contribute exp2(0)=1 each
    se -= labexp[b];        // remove fp8 label column
    float cl = coslab[b];
    float sine = sqrtf(fmaxf(0.f, 1.f - cl * cl));
    float phi = cl * COSM - sine * SINM;
    if (!(cl - THC > 0.f)) phi = cl - MMC;
    arc += __logf(se + exp2f(K2C * phi)) - SSCALE * phi;
  }
#pragma unroll
  for (int i = 0; i < 4; i++) {
    float4 p = tvpart[i * 256 + t];
    hs += p.x; wsm += p.y; bs += p.z;
  }
  fs = (t < S2_GEMM0) ? fftpart[t] : 0.f;
  arc = waveRedSum(arc); hs = waveRedSum(hs); wsm = waveRedSum(wsm);
  bs = waveRedSum(bs); fs = waveRedSum(fs);
  __shared__ float red[5][4];
  if ((t & 63) == 0) {
    int w = t >> 6;
    red[0][w] = arc; red[1][w] = hs; red[2][w] = wsm; red[3][w] = bs; red[4][w] = fs;
  }
  __syncthreads();
  if (t == 0) {
    float A = 0, H = 0, Wv = 0, Bv = 0, F = 0;
#pragma unroll
    for (int w = 0; w < 4; w++) {
      A += red[0][w]; H += red[1][w]; Wv += red[2][w]; Bv += red[3][w]; F += red[4][w];
    }
    float cnt2 = 1023.0f * 1024.0f;
    out[0] = A * (1.0f / 512.0f) - 2.0f * (H / cnt2 + Wv / cnt2)
           + Bv * (1.0f / 1048576.0f) + F;
  }
}

extern "C" void kernel_launch(void* const* d_in, const int* in_sizes, int n_in,
                              void* d_out, int out_size, void* d_ws, size_t ws_size,
                              hipStream_t stream) {
  const float* x = (const float*)d_in[0];
  const int* label = (const int*)d_in[1];
  const float* kimg = (const float*)d_in[2];
  // d_in[3]=x0, d_in[4]=img — unused by the reference loss
  const float* W = (const float*)d_in[5];
  float* out = (float*)d_out;
  char* ws = (char*)d_ws;
  float*  coslab  = (float*)(ws + 0);
  char*   xh8     = (char*)(ws + 2048);
  char*   Wh8     = (char*)(ws + 67584);
  float2* fbuf    = (float2*)(ws + 12879872);  // 1024 x 516 float2
  float*  gpart   = (float*)(ws + 17106944);   // 1564*512*4
  float*  g2      = (float*)(ws + 20310016);   // 64*512*4 = 131072
  float4* tvpart  = (float4*)(ws + 20441088);  // 1024 float4
  float*  fftpart = (float*)(ws + 20457472);
  float*  labexp  = (float*)(ws + 20459520);
  int*    cnt     = (int*)(ws + 20461568);

  hipLaunchKernelGGL(stage1_k, dim3(S1_NW), dim3(256), 0, stream,
                     x, W, label, kimg, xh8, coslab, Wh8, fbuf, cnt);
  hipLaunchKernelGGL(stage2_k, dim3(S2_NBLK), dim3(256), 0, stream,
                     Wh8, xh8, gpart, fbuf, fftpart, kimg, tvpart);
  hipLaunchKernelGGL(gemmred_k, dim3(GR_NBLK), dim3(256), 0, stream,
                     gpart, g2, xh8, Wh8, label, labexp,
                     coslab, tvpart, fftpart, cnt, out);
}

// Round 16
// 138.978 us; speedup vs baseline: 1.0137x; 1.0137x over previous
//
#include <hip/hip_runtime.h>

// hybridloss: arcface CE (512x100000x128 fp8-MFMA GEMM + exp-sum softmax)
//           + TV loss + bin loss + sum|FFT2(k)| (1024x1024, REAL input).
// R16 = R14 verbatim (measured best: 139.6us). R15's dial-notches (normW-64,
//   gemmred-128) both regressed (serialized per-lane reduce chains) and are
//   reverted. Final structure:
//   - stage1: row-pair real FFT (Hermitian unpack, cols 0..512) | xprep | normW-32
//   - stage2: fftcol(129, weighted cols) | fp8 1-barrier GEMM (XCD mod-8 grouping,
//     XOR-swizzled LDS, unmasked exp2 epilogue) | tvbin
//   - gemmred: 64 reduce + 2 labexp blocks, last-block-done final reduction.
// Workspace layout (bytes), total ~20.4 MB (ws is 256 MiB):
//   [0,2048)              coslab[512]
//   [2048,67584)          xh8: 512x128 fp8
//   [67584,12879872)      Wh8: 100096x128 fp8 (pad rows zeroed)
//   [12879872,17106944)   fbuf: 1024 rows x 516 cols float2
//   [17106944,20310016)   gpart[1564][512]
//   [20310016,20375552)   g2[32][512]
//   [20375552,20391936)   tvpart[1024] float4
//   [20391936,20393984)   fftpart[129] (padded)
//   [20393984,20396032)   labexp[512]
//   [20396032,20396036)   cnt (last-block counter, zeroed by stage1)

typedef float f32x4 __attribute__((ext_vector_type(4)));
typedef unsigned short u16;
typedef unsigned int u32;
typedef unsigned long long u64;

#define BATCH 512
#define DIM 128
#define OUTN 100000
#define NOBLK 782
#define NROW2 1564      // gpart rows
#define CHUNKS 32
#define CHSZ2 49        // 32*49 = 1568 >= 1564
#define NCOL 516
#define SSCALE 32.0f
#define K2C 46.166241308446828f   // 32 * log2(e)
#define COSM 0.8775825618903728f
#define SINM 0.479425538604203f
#define THC (-0.8775825618903728f)
#define MMC 0.2397127693021015f

// stage1 roles (blockIdx.x): fftrow(pairs) | xprep | normW (32 rows/block)
#define S1_FFT 512
#define S1_XP  640
#define S1_NW  3768    // 640 + 3128

// stage2 roles: [0,129) fftcol; [129,129+3136) gemm (98 groups of 32); then tvbin
#define S2_GEMM0 129
#define S2_TV0   3265
#define S2_NBLK  4289

// gemmred: blocks 0..63 reduce, 64..65 labexp; last of 66 finalizes
#define GR_NBLK 66

#define DEC8(v, j) __builtin_amdgcn_cvt_f32_fp8((int)(v), (j))

__device__ inline float waveRedSum(float v) {
#pragma unroll
  for (int off = 1; off < 64; off <<= 1) v += __shfl_xor(v, off, 64);
  return v;
}

__device__ inline float quadRedSum(float v) {   // reduce within each 16-lane group
#pragma unroll
  for (int off = 1; off < 16; off <<= 1) v += __shfl_xor(v, off, 64);
  return v;
}

// ---------------- stage 1: fftrow-pairs | xprep | normW ----------------
__global__ __launch_bounds__(256) void stage1_k(const float* __restrict__ x,
                                                const float* __restrict__ W,
                                                const int* __restrict__ label,
                                                const float* __restrict__ kimg,
                                                char* __restrict__ xh8,
                                                float* __restrict__ coslab,
                                                char* __restrict__ Wh8,
                                                float2* __restrict__ fbuf,
                                                int* __restrict__ cnt) {
  __shared__ __align__(16) char smem[12288];   // tw[512]f2 + arr[1024]f2
  int t = threadIdx.x;
  int bid = blockIdx.x;

  if (bid < S1_FFT) {
    // ---- row-pair FFT: z = row(2r) + i*row(2r+1), 1024-pt DIF, Hermitian unpack ----
    float2* tw = (float2*)smem;          // tw[j] = (cos,sin)(-2*pi*j/1024)
    float2* arr = (float2*)(smem + 4096);
    int r = bid;
#pragma unroll
    for (int i = 0; i < 2; i++) {
      int j = i * 256 + t;
      float s, c;
      __sincosf(-0.006135923151542565f * (float)j, &s, &c);  // -2pi/1024 * j
      tw[j] = make_float2(c, s);
    }
#pragma unroll
    for (int i = 0; i < 4; i++) {
      int idx = i * 256 + t;
      arr[idx] = make_float2(kimg[(2 * r) * 1024 + idx], kimg[(2 * r + 1) * 1024 + idx]);
    }
    __syncthreads();
    for (int lh = 9; lh >= 0; lh--) {
      int hlf = 1 << lh;
#pragma unroll
      for (int i = 0; i < 2; i++) {
        int bf = i * 256 + t;
        int pos = bf & (hlf - 1);
        int g = bf >> lh;
        int i0 = (g << (lh + 1)) + pos;
        int i1 = i0 + hlf;
        float2 u = arr[i0], v = arr[i1];
        float2 w = tw[pos << (9 - lh)];
        arr[i0] = make_float2(u.x + v.x, u.y + v.y);
        float dr = u.x - v.x, di = u.y - v.y;
        arr[i1] = make_float2(dr * w.x - di * w.y, dr * w.y + di * w.x);
      }
      __syncthreads();
    }
    // arr[br10(k)] = Z(k). Unpack k=0..512 (cols 513..515 zeroed).
#pragma unroll
    for (int it = 0; it < 3; it++) {
      int k = it * 256 + t;
      if (k < NCOL) {
        float2 fa = make_float2(0.f, 0.f), fb = make_float2(0.f, 0.f);
        if (k < 513) {
          int j1 = __brev((u32)k) >> 22;
          int j2 = __brev((u32)((1024 - k) & 1023)) >> 22;
          float2 z1 = arr[j1], z2 = arr[j2];
          fa = make_float2(0.5f * (z1.x + z2.x), 0.5f * (z1.y - z2.y));
          float uu = z1.x - z2.x, vv = z1.y + z2.y;
          fb = make_float2(0.5f * vv, -0.5f * uu);
        }
        fbuf[(size_t)(2 * r) * NCOL + k] = fa;
        fbuf[(size_t)(2 * r + 1) * NCOL + k] = fb;
      }
    }
  } else if (bid < S1_XP) {
    // ---- x normalize -> fp8 + fp32 cosine(x_b, W[label_b]) ----
    if (bid == S1_FFT && t == 0) *cnt = 0;   // zero the last-block counter
    int b = (bid - S1_FFT) * 4 + (t >> 6);
    int lane = t & 63;
    size_t xb = (size_t)b * DIM;
    float2 v = *(const float2*)&x[xb + lane * 2];
    int lab = label[b];
    size_t wb = (size_t)lab * DIM;
    float2 w = *(const float2*)&W[wb + lane * 2];
    float ss = waveRedSum(v.x * v.x + v.y * v.y);
    float d  = waveRedSum(v.x * w.x + v.y * w.y);
    float nw = waveRedSum(w.x * w.x + w.y * w.y);
    float inv = rsqrtf(ss);
    u32 pk = __builtin_amdgcn_cvt_pk_fp8_f32(v.x * inv, v.y * inv, 0, 0);
    *(u16*)&xh8[b * 128 + lane * 2] = (u16)pk;
    if (lane == 0) coslab[b] = d * rsqrtf(ss * nw);
  } else {
    // ---- W normalize -> fp8: 32 rows/block, 2 rows per 16-lane group ----
    int rA = (bid - S1_XP) * 32 + (t >> 4) * 2;   // rows rA, rA+1
    int g16 = t & 15;
    if (rA >= OUTN) {                              // OUTN%32==0 -> group-uniform
      *(uint2*)&Wh8[(size_t)rA * 128 + g16 * 8] = make_uint2(0u, 0u);
      *(uint2*)&Wh8[(size_t)(rA + 1) * 128 + g16 * 8] = make_uint2(0u, 0u);
      return;
    }
    const float* wrA = &W[(size_t)rA * DIM + g16 * 8];
    const float* wrB = &W[(size_t)(rA + 1) * DIM + g16 * 8];
    float4 a0 = *(const float4*)wrA;
    float4 a1 = *(const float4*)(wrA + 4);
    float4 b0 = *(const float4*)wrB;
    float4 b1 = *(const float4*)(wrB + 4);
    float ssA = quadRedSum(a0.x * a0.x + a0.y * a0.y + a0.z * a0.z + a0.w * a0.w
                         + a1.x * a1.x + a1.y * a1.y + a1.z * a1.z + a1.w * a1.w);
    float ssB = quadRedSum(b0.x * b0.x + b0.y * b0.y + b0.z * b0.z + b0.w * b0.w
                         + b1.x * b1.x + b1.y * b1.y + b1.z * b1.z + b1.w * b1.w);
    float invA = rsqrtf(ssA), invB = rsqrtf(ssB);
    u32 lo = __builtin_amdgcn_cvt_pk_fp8_f32(a0.x * invA, a0.y * invA, 0, 0);
    lo = __builtin_amdgcn_cvt_pk_fp8_f32(a0.z * invA, a0.w * invA, lo, 1);
    u32 hi = __builtin_amdgcn_cvt_pk_fp8_f32(a1.x * invA, a1.y * invA, 0, 0);
    hi = __builtin_amdgcn_cvt_pk_fp8_f32(a1.z * invA, a1.w * invA, hi, 1);
    *(uint2*)&Wh8[(size_t)rA * 128 + g16 * 8] = make_uint2(lo, hi);
    lo = __builtin_amdgcn_cvt_pk_fp8_f32(b0.x * invB, b0.y * invB, 0, 0);
    lo = __builtin_amdgcn_cvt_pk_fp8_f32(b0.z * invB, b0.w * invB, lo, 1);
    hi = __builtin_amdgcn_cvt_pk_fp8_f32(b1.x * invB, b1.y * invB, 0, 0);
    hi = __builtin_amdgcn_cvt_pk_fp8_f32(b1.z * invB, b1.w * invB, hi, 1);
    *(uint2*)&Wh8[(size_t)(rA + 1) * 128 + g16 * 8] = make_uint2(lo, hi);
  }
}

// ---------------- stage 2: fftcol(129) | fp8 gemm (1 barrier) | tvbin ----------------
__global__ __launch_bounds__(256, 4) void stage2_k(const char* __restrict__ Wh8,
                                                   const char* __restrict__ xh8,
                                                   float* __restrict__ gpart,
                                                   const float2* __restrict__ fbuf,
                                                   float* __restrict__ fftpart,
                                                   const float* __restrict__ kimg,
                                                   float4* __restrict__ tvpart) {
  __shared__ __align__(16) char smem[36880];
  int t = threadIdx.x;
  int bid = blockIdx.x;

  if (bid >= S2_TV0) {
    // ---- TV + bin loss, one image row per block ----
    int r = bid - S2_TV0;
    int idx = r * 1024 + t * 4;
    float4 v = *(const float4*)&kimg[idx];
    float bs = v.x * v.x + (v.x - 1.f) * (v.x - 1.f)
             + v.y * v.y + (v.y - 1.f) * (v.y - 1.f)
             + v.z * v.z + (v.z - 1.f) * (v.z - 1.f)
             + v.w * v.w + (v.w - 1.f) * (v.w - 1.f);
    float d0 = v.y - v.x, d1 = v.z - v.y, d2 = v.w - v.z;
    float wsm = d0 * d0 + d1 * d1 + d2 * d2;
    if (t < 255) { float e4 = kimg[idx + 4]; float d3 = e4 - v.w; wsm += d3 * d3; }
    float hs = 0.f;
    if (r < 1023) {
      float4 n = *(const float4*)&kimg[idx + 1024];
      float h0 = n.x - v.x, h1 = n.y - v.y, h2 = n.z - v.z, h3 = n.w - v.w;
      hs = h0 * h0 + h1 * h1 + h2 * h2 + h3 * h3;
    }
    hs = waveRedSum(hs); wsm = waveRedSum(wsm); bs = waveRedSum(bs);
    float (*red)[4] = (float(*)[4])smem;
    if ((t & 63) == 0) { int w = t >> 6; red[0][w] = hs; red[1][w] = wsm; red[2][w] = bs; }
    __syncthreads();
    if (t == 0)
      tvpart[r] = make_float4(red[0][0] + red[0][1] + red[0][2] + red[0][3],
                              red[1][0] + red[1][1] + red[1][2] + red[1][3],
                              red[2][0] + red[2][1] + red[2][2] + red[2][3], 0.f);
  } else if (bid >= S2_GEMM0) {
    // ---- GEMM role: 128(o) x 128(b), K=128 fp8, both tiles full-K in LDS ----
    int wgrp = (bid - S2_GEMM0) & 31, g = (bid - S2_GEMM0) >> 5;
    int o = g * 8 + (wgrp & 7), bt = wgrp >> 3;  // same-o blocks 8 apart -> same XCD
    if (o >= NOBLK) return;
    int o0 = o * 128, b0 = bt * 128;
    char* Ash = smem;                 // 128 rows x 16 chunks(8B), chunk' = c ^ (r&15)
    char* Bsh = smem + 16384;
    int wv = t >> 6, lane = t & 63;
    int wo = (wv & 1) << 6, wbs = (wv >> 1) << 6;
    int m16 = lane & 15, q = lane >> 4;

    // Stage both tiles (16 KB each), then ONE barrier.
    int r8 = t >> 3, cB = (t & 7) * 16, c0 = (t & 7) * 2;
#pragma unroll
    for (int it = 0; it < 4; it++) {
      int r = it * 32 + r8;
      int s = r & 15;
      uint4 va = *(const uint4*)&Wh8[(size_t)(o0 + r) * 128 + cB];
      *(u64*)&Ash[r * 128 + ((c0 ^ s) << 3)]       = ((u64)va.y << 32) | va.x;
      *(u64*)&Ash[r * 128 + (((c0 + 1) ^ s) << 3)] = ((u64)va.w << 32) | va.z;
      uint4 vb = *(const uint4*)&xh8[(size_t)(b0 + r) * 128 + cB];
      *(u64*)&Bsh[r * 128 + ((c0 ^ s) << 3)]       = ((u64)vb.y << 32) | vb.x;
      *(u64*)&Bsh[r * 128 + (((c0 + 1) ^ s) << 3)] = ((u64)vb.w << 32) | vb.z;
    }
    __syncthreads();

    f32x4 acc[4][4] = {};
#pragma unroll
    for (int kk = 0; kk < 4; kk++) {
      long af[4], bf[4];
#pragma unroll
      for (int i = 0; i < 4; i++) {
        int row = wo + i * 16 + m16;
        af[i] = *(const long*)&Ash[row * 128 + (((kk * 4 + q) ^ (row & 15)) << 3)];
      }
#pragma unroll
      for (int j = 0; j < 4; j++) {
        int row = wbs + j * 16 + m16;
        bf[j] = *(const long*)&Bsh[row * 128 + (((kk * 4 + q) ^ (row & 15)) << 3)];
      }
#pragma unroll
      for (int i = 0; i < 4; i++)
#pragma unroll
        for (int j = 0; j < 4; j++)
          acc[i][j] = __builtin_amdgcn_mfma_f32_16x16x32_fp8_fp8(af[i], bf[j], acc[i][j], 0, 0, 0);
    }
    // Epilogue: unmasked exp2 sums (pad rows -> exp2(0)=1, subtracted in final).
#pragma unroll
    for (int j = 0; j < 4; j++) {
      float s = 0.f;
#pragma unroll
      for (int i = 0; i < 4; i++)
#pragma unroll
        for (int r = 0; r < 4; r++)
          s += exp2f(K2C * acc[i][j][r]);
      s += __shfl_xor(s, 16, 64);   // fold q-quadrants (same b, different o)
      s += __shfl_xor(s, 32, 64);
      if (q == 0)
        gpart[(size_t)(o * 2 + (wv & 1)) * 512 + b0 + wbs + j * 16 + m16] = s;
    }
  } else {
    // ---- column FFT role (bids 0..128): 4 cols/block of fbuf[1024][516],
    //      weights: col0 & col512 x1, cols 1..511 x2, cols 513+ zero data ----
    float2* arr = (float2*)smem;          // 4096 float2 = 32 KB
    float2* tw = (float2*)(smem + 32768); // 512 float2 = 4 KB
    float* red = (float*)(smem + 36864);
    int c0 = bid * 4;
#pragma unroll
    for (int i = 0; i < 2; i++) {
      int j = i * 256 + t;
      float s, c;
      __sincosf(-0.006135923151542565f * (float)j, &s, &c);  // -2pi/1024 * j
      tw[j] = make_float2(c, s);
    }
#pragma unroll
    for (int i = 0; i < 16; i++) {
      int li = i * 256 + t;
      int rr = li >> 2, c = li & 3;
      arr[rr * 4 + c] = fbuf[(size_t)rr * NCOL + c0 + c];
    }
    __syncthreads();
    for (int lh = 9; lh >= 0; lh--) {
      int hlf = 1 << lh;
#pragma unroll
      for (int i = 0; i < 8; i++) {
        int w = i * 256 + t;
        int c = w & 3, bf = w >> 2;
        int pos = bf & (hlf - 1), g2i = bf >> lh;
        int i0 = ((g2i << (lh + 1)) + pos) * 4 + c;
        int i1 = i0 + hlf * 4;
        float2 u = arr[i0], v = arr[i1];
        float2 tww = tw[pos << (9 - lh)];
        arr[i0] = make_float2(u.x + v.x, u.y + v.y);
        float dr = u.x - v.x, di = u.y - v.y;
        arr[i1] = make_float2(dr * tww.x - di * tww.y, dr * tww.y + di * tww.x);
      }
      __syncthreads();
    }
    float s = 0.f;
#pragma unroll
    for (int i = 0; i < 16; i++) {
      int li = i * 256 + t;
      int col = c0 + (li & 3);
      float w = (col == 0 || col == 512) ? 1.f : (col < 512 ? 2.f : 0.f);
      float2 v = arr[li];
      s += w * sqrtf(v.x * v.x + v.y * v.y);
    }
    s = waveRedSum(s);
    if ((t & 63) == 0) red[t >> 6] = s;
    __syncthreads();
    if (t == 0) fftpart[bid] = red[0] + red[1] + red[2] + red[3];
  }
}

// blocks 0..63: reduce gpart -> g2[32][512]; blocks 64..65: labexp.
// LAST block to finish (device atomic) computes the final scalar loss.
__global__ __launch_bounds__(256) void gemmred_k(const float* __restrict__ gpart,
                                                 float* __restrict__ g2,
                                                 const char* __restrict__ xh8,
                                                 const char* __restrict__ Wh8,
                                                 const int* __restrict__ label,
                                                 float* __restrict__ labexp,
                                                 const float* __restrict__ coslab,
                                                 const float4* __restrict__ tvpart,
                                                 const float* __restrict__ fftpart,
                                                 int* __restrict__ cnt,
                                                 float* __restrict__ out) {
  int t = threadIdx.x;
  int blk = blockIdx.x;
  if (blk < 64) {
    int chunk = blk >> 1, half = blk & 1;
    int b = half * 256 + t;
    int rBeg = chunk * CHSZ2;
    int rEnd = rBeg + CHSZ2; if (rEnd > NROW2) rEnd = NROW2;
    float s = 0.f;
    for (int r = rBeg; r < rEnd; r++) s += gpart[(size_t)r * 512 + b];
    g2[chunk * 512 + b] = s;
  } else {
    int b = (blk - 64) * 256 + t;
    int lab = label[b];
    const u32* xr = (const u32*)(xh8 + (size_t)b * 128);
    const u32* wr = (const u32*)(Wh8 + (size_t)lab * 128);
    float d = 0.f;
#pragma unroll 4
    for (int i = 0; i < 32; i++) {
      u32 xa = xr[i], wa = wr[i];
      d += DEC8(xa, 0) * DEC8(wa, 0) + DEC8(xa, 1) * DEC8(wa, 1)
         + DEC8(xa, 2) * DEC8(wa, 2) + DEC8(xa, 3) * DEC8(wa, 3);
    }
    labexp[b] = exp2f(K2C * d);
  }

  // ---- last-block-done final reduction ----
  __shared__ int lastFlag;
  __threadfence();                       // release: g2/labexp visible device-wide
  __syncthreads();
  if (t == 0) lastFlag = (atomicAdd(cnt, 1) == GR_NBLK - 1);
  __syncthreads();
  if (!lastFlag) return;
  __threadfence();                       // acquire

  float arc = 0.f, hs = 0.f, wsm = 0.f, bs = 0.f, fs = 0.f;
#pragma unroll
  for (int i = 0; i < 2; i++) {
    int b = i * 256 + t;
    float se = 0.f;
#pragma unroll
    for (int c = 0; c < CHUNKS; c++) se += g2[c * 512 + b];
    se -= 96.0f;            // 100096-100000 zero rows contribute exp2(0)=1 each
    se -= labexp[b];        // remove fp8 label column
    float cl = coslab[b];
    float sine = sqrtf(fmaxf(0.f, 1.f - cl * cl));
    float phi = cl * COSM - sine * SINM;
    if (!(cl - THC > 0.f)) phi = cl - MMC;
    arc += __logf(se + exp2f(K2C * phi)) - SSCALE * phi;
  }
#pragma unroll
  for (int i = 0; i < 4; i++) {
    float4 p = tvpart[i * 256 + t];
    hs += p.x; wsm += p.y; bs += p.z;
  }
  fs = (t < S2_GEMM0) ? fftpart[t] : 0.f;
  arc = waveRedSum(arc); hs = waveRedSum(hs); wsm = waveRedSum(wsm);
  bs = waveRedSum(bs); fs = waveRedSum(fs);
  __shared__ float red[5][4];
  if ((t & 63) == 0) {
    int w = t >> 6;
    red[0][w] = arc; red[1][w] = hs; red[2][w] = wsm; red[3][w] = bs; red[4][w] = fs;
  }
  __syncthreads();
  if (t == 0) {
    float A = 0, H = 0, Wv = 0, Bv = 0, F = 0;
#pragma unroll
    for (int w = 0; w < 4; w++) {
      A += red[0][w]; H += red[1][w]; Wv += red[2][w]; Bv += red[3][w]; F += red[4][w];
    }
    float cnt2 = 1023.0f * 1024.0f;
    out[0] = A * (1.0f / 512.0f) - 2.0f * (H / cnt2 + Wv / cnt2)
           + Bv * (1.0f / 1048576.0f) + F;
  }
}

extern "C" void kernel_launch(void* const* d_in, const int* in_sizes, int n_in,
                              void* d_out, int out_size, void* d_ws, size_t ws_size,
                              hipStream_t stream) {
  const float* x = (const float*)d_in[0];
  const int* label = (const int*)d_in[1];
  const float* kimg = (const float*)d_in[2];
  // d_in[3]=x0, d_in[4]=img — unused by the reference loss
  const float* W = (const float*)d_in[5];
  float* out = (float*)d_out;
  char* ws = (char*)d_ws;
  float*  coslab  = (float*)(ws + 0);
  char*   xh8     = (char*)(ws + 2048);
  char*   Wh8     = (char*)(ws + 67584);
  float2* fbuf    = (float2*)(ws + 12879872);  // 1024 x 516 float2
  float*  gpart   = (float*)(ws + 17106944);   // 1564*512*4
  float*  g2      = (float*)(ws + 20310016);   // 32*512*4
  float4* tvpart  = (float4*)(ws + 20375552);  // 1024 float4
  float*  fftpart = (float*)(ws + 20391936);
  float*  labexp  = (float*)(ws + 20393984);
  int*    cnt     = (int*)(ws + 20396032);

  hipLaunchKernelGGL(stage1_k, dim3(S1_NW), dim3(256), 0, stream,
                     x, W, label, kimg, xh8, coslab, Wh8, fbuf, cnt);
  hipLaunchKernelGGL(stage2_k, dim3(S2_NBLK), dim3(256), 0, stream,
                     Wh8, xh8, gpart, fbuf, fftpart, kimg, tvpart);
  hipLaunchKernelGGL(gemmred_k, dim3(GR_NBLK), dim3(256), 0, stream,
                     gpart, g2, xh8, Wh8, label, labexp,
                     coslab, tvpart, fftpart, cnt, out);
}